// Round 9
// baseline (2689.262 us; speedup 1.0000x reference)
//
#include <hip/hip_runtime.h>
#include <hip/hip_bf16.h>
#include <cstdint>
#include <cstddef>

// ---------------------------------------------------------------------------
// DVAE forward v8: v7 + coalesced full-cell epilogues.
// Round-8 diagnosis: convM/deconvM epilogues wrote 8B pieces at 32/64B stride
// -> 9.3x HBM write amplification (c3: 157MB vs 16.8MB ideal), write-path
// bound at MfmaUtil 28%. Fix: half-wave exchange — lane kh=0 holds words
// {0,1,4,5} of each 16-ch cell, kh=1 holds {2,3,6,7}; 4 __shfl_xor(,32)
// per cell (8 w/ lo-plane) lets every lane store a full 32B cell (two
// adjacent uint4s). deconvM pairs px=0/1 so each lane writes 64B contiguous.
// Packing math unchanged -> bit-identical values.
// ---------------------------------------------------------------------------

#define B 8

typedef __attribute__((ext_vector_type(8)))  short  short8;
typedef __attribute__((ext_vector_type(4)))  short  short4v;
typedef __attribute__((ext_vector_type(16))) float  f32x16;

__device__ inline unsigned short f2bf(float x) {          // RNE f32->bf16
    uint32_t u = __float_as_uint(x);
    uint32_t r = (u + 0x7FFFu + ((u >> 16) & 1u)) >> 16;
    return (unsigned short)r;
}
__device__ inline float bf2f(unsigned short h) {
    return __uint_as_float(((uint32_t)h) << 16);
}
__device__ inline uint32_t pack2(float a, float b) {
    return (uint32_t)f2bf(a) | ((uint32_t)f2bf(b) << 16);
}

// ---------------- encoder strided conv (Cin=3, Cout=4, k=3, pad=1) ----------
__global__ void enc_conv_kernel(const float* __restrict__ x, const float* __restrict__ w,
                                const float* __restrict__ bias, float* __restrict__ out,
                                int S, int HO) {
    int id = blockIdx.x * 256 + threadIdx.x;
    int total = B * 4 * HO * HO;
    if (id >= total) return;
    int ox = id % HO, oy = (id / HO) % HO, co = (id / (HO * HO)) % 4, b = id / (HO * HO * 4);
    float acc = bias[co];
    for (int ci = 0; ci < 3; ++ci) {
        const float* xp = x + ((size_t)b * 3 + ci) * 65536;
        const float* wp = w + (co * 3 + ci) * 9;
        #pragma unroll
        for (int ky = 0; ky < 3; ++ky) {
            int iy = oy * S - 1 + ky;
            if (iy < 0 || iy >= 256) continue;
            #pragma unroll
            for (int kx = 0; kx < 3; ++kx) {
                int ix = ox * S - 1 + kx;
                if (ix < 0 || ix >= 256) continue;
                acc = fmaf(xp[iy * 256 + ix], wp[ky * 3 + kx], acc);
            }
        }
    }
    out[id] = acc;
}

// ---------------- entropy (KDE), gray fused ----------------
__global__ __launch_bounds__(256) void entropy_kernel(const float* __restrict__ x,
                                                      float* __restrict__ ent) {
    __shared__ float s_patch[256];
    __shared__ float s_red[4];
    int blk = blockIdx.x;
    int b = blk >> 8, rem = blk & 255;
    int py = rem >> 4, px = rem & 15;
    int tid = threadIdx.x;
    int pr = tid >> 4, pc = tid & 15;
    const float* xb = x + (size_t)b * 3 * 65536;
    int p = (py * 16 + pr) * 256 + (px * 16 + pc);
    s_patch[tid] = 0.299f * xb[p] + 0.587f * xb[65536 + p] + 0.114f * xb[2 * 65536 + p];
    __syncthreads();

    float bin = (float)tid * (1.0f / 255.0f);
    float s = 0.f;
    #pragma unroll 8
    for (int q = 0; q < 256; ++q) {
        float t = (s_patch[q] - bin) * 100.0f;
        s += expf(-0.5f * (t * t));
    }
    float pdf = s * (1.0f / 256.0f);

    float r = pdf;
    #pragma unroll
    for (int o = 32; o > 0; o >>= 1) r += __shfl_down(r, o, 64);
    if ((tid & 63) == 0) s_red[tid >> 6] = r;
    __syncthreads();
    float total = s_red[0] + s_red[1] + s_red[2] + s_red[3];
    __syncthreads();

    float p2 = pdf / total;
    p2 = fmaxf(p2, 1e-10f);
    float e = -p2 * log2f(p2);
    #pragma unroll
    for (int o = 32; o > 0; o >>= 1) e += __shfl_down(e, o, 64);
    if ((tid & 63) == 0) s_red[tid >> 6] = e;
    __syncthreads();
    if (tid == 0) ent[blk] = s_red[0] + s_red[1] + s_red[2] + s_red[3];
}

// ---------------- median of 2048 values (bitonic sort) ----------------
__global__ __launch_bounds__(1024) void median_kernel(const float* __restrict__ ent,
                                                      float* __restrict__ thr) {
    __shared__ float s[2048];
    int tid = threadIdx.x;
    s[tid] = ent[tid];
    s[tid + 1024] = ent[tid + 1024];
    __syncthreads();
    for (int k = 2; k <= 2048; k <<= 1) {
        for (int j = k >> 1; j > 0; j >>= 1) {
            int t = tid;
            #pragma unroll 1
            for (int rep = 0; rep < 2; ++rep, t += 1024) {
                int ixj = t ^ j;
                if (ixj > t) {
                    float a = s[t], bb = s[ixj];
                    bool up = ((t & k) == 0);
                    bool sw = up ? (a > bb) : (a < bb);
                    if (sw) { s[t] = bb; s[ixj] = a; }
                }
            }
            __syncthreads();
        }
    }
    if (tid == 0) *thr = 0.5f * (s[1023] + s[1024]);
}

__global__ void grain_kernel(const float* __restrict__ ent, const float* __restrict__ thr,
                             float* __restrict__ grain) {
    int id = blockIdx.x * 256 + threadIdx.x;
    if (id >= 2048) return;
    grain[id] = (ent[id] > *thr) ? 1.0f : 0.0f;
}

__global__ void route_kernel(const float* __restrict__ latf, const float* __restrict__ latc,
                             const float* __restrict__ grain, float* __restrict__ routed) {
    int id = blockIdx.x * 256 + threadIdx.x;
    if (id >= B * 4 * 32 * 32) return;
    int xx = id & 31, yy = (id >> 5) & 31, c = (id >> 10) & 3, b = id >> 12;
    float g = grain[b * 256 + (yy >> 1) * 16 + (xx >> 1)];
    float cu = latc[((b * 4 + c) * 16 + (yy >> 1)) * 16 + (xx >> 1)];
    routed[id] = g * latf[id] + (1.0f - g) * cu;
}

// ---------------- fp32 conv3x3 (Wi -> A-format) ----------------
template<int CIN, int COUT, int H, int W, int CI_BLK, int CO_BLK>
__global__ __launch_bounds__(256) void conv3x3A(const float* __restrict__ in,
                                                const float* __restrict__ wgt,
                                                const float* __restrict__ bias,
                                                unsigned short* __restrict__ outA) {
    constexpr int TW = W / 16;
    __shared__ float s_in[CI_BLK][18][18];
    __shared__ float s_w[CI_BLK][9][CO_BLK];
    const int tid = threadIdx.x;
    const int lx = tid & 15, ly = tid >> 4;
    const int co0 = blockIdx.x * CO_BLK;
    const int tile = blockIdx.y;
    const int tx0 = (tile % TW) * 16, ty0 = (tile / TW) * 16;
    const int ox = tx0 + lx, oy = ty0 + ly;

    float acc[CO_BLK];
    #pragma unroll
    for (int i = 0; i < CO_BLK; ++i) acc[i] = bias[co0 + i];

    for (int ci0 = 0; ci0 < CIN; ci0 += CI_BLK) {
        for (int idx = tid; idx < CI_BLK * 324; idx += 256) {
            int ci = idx / 324, rm = idx % 324;
            int r = rm / 18, c = rm % 18;
            int iy = ty0 - 1 + r, ix = tx0 - 1 + c;
            float v = 0.f;
            if (iy >= 0 && iy < H && ix >= 0 && ix < W)
                v = in[((size_t)(ci0 + ci) * H + iy) * W + ix];
            s_in[ci][r][c] = v;
        }
        for (int idx = tid; idx < CI_BLK * 9 * CO_BLK; idx += 256) {
            int ci = idx / (9 * CO_BLK), rm = idx % (9 * CO_BLK);
            int k = rm / CO_BLK, co = rm % CO_BLK;
            s_w[ci][k][co] = wgt[((size_t)(co0 + co) * CIN + ci0 + ci) * 9 + k];
        }
        __syncthreads();
        #pragma unroll
        for (int ci = 0; ci < CI_BLK; ++ci) {
            float v[9];
            #pragma unroll
            for (int ky = 0; ky < 3; ++ky)
                #pragma unroll
                for (int kx = 0; kx < 3; ++kx)
                    v[ky * 3 + kx] = s_in[ci][ly + ky][lx + kx];
            #pragma unroll
            for (int k = 0; k < 9; ++k) {
                #pragma unroll
                for (int c4 = 0; c4 < CO_BLK / 4; ++c4) {
                    const float4 w4 = *reinterpret_cast<const float4*>(&s_w[ci][k][c4 * 4]);
                    acc[c4 * 4 + 0] = fmaf(v[k], w4.x, acc[c4 * 4 + 0]);
                    acc[c4 * 4 + 1] = fmaf(v[k], w4.y, acc[c4 * 4 + 1]);
                    acc[c4 * 4 + 2] = fmaf(v[k], w4.z, acc[c4 * 4 + 2]);
                    acc[c4 * 4 + 3] = fmaf(v[k], w4.w, acc[c4 * 4 + 3]);
                }
            }
        }
        __syncthreads();
    }
    #pragma unroll
    for (int co = 0; co < CO_BLK; ++co) {
        float v = acc[co];
        int c = co0 + co;
        unsigned short h = f2bf(v);
        unsigned short l = f2bf(v - bf2f(h));
        size_t a = ((size_t)(c >> 4) * H * W + (size_t)oy * W + ox) * 16 + (c & 15);
        outA[a] = h;
        outA[a + (size_t)H * W * COUT] = l;
    }
}

// ---------------- fused weight pre-split (runs ONCE) ------------------------
// unified slot layout (conv AND deconv): [cob32][ch][hl][kh][t][co32][ci8]
__device__ inline void wsplit_conv_one(const float* __restrict__ w, unsigned short* dst,
                                       int CIN, int idx) {
    int t = idx % 9;
    int ci = (idx / 9) % CIN;
    int co = idx / (9 * CIN);
    float x = w[idx];                   // w[co][ci][t]
    unsigned short h = f2bf(x);
    unsigned short l = f2bf(x - bf2f(h));
    int CH = CIN >> 4;
    int cob = co >> 5, col = co & 31;
    int ch = ci >> 4, kh = (ci >> 3) & 1, ci8 = ci & 7;
    size_t base = (size_t)(cob * CH + ch) * 9216 + (size_t)((kh * 9 + t) * 256) + col * 8 + ci8;
    dst[base] = h;
    dst[base + 4608] = l;
}
__device__ inline void wsplit_deconv_one(const float* __restrict__ w, unsigned short* dst,
                                         int CIN, int COUT, int idx) {
    int t = idx % 9;
    int co = (idx / 9) % COUT;
    int ci = idx / (9 * COUT);
    float x = w[idx];                   // w[ci][co][t]
    unsigned short h = f2bf(x);
    unsigned short l = f2bf(x - bf2f(h));
    int CH = CIN >> 4;
    int cob = co >> 5, col = co & 31;
    int ch = ci >> 4, kh = (ci >> 3) & 1, ci8 = ci & 7;
    size_t base = (size_t)(cob * CH + ch) * 9216 + (size_t)((kh * 9 + t) * 256) + col * 8 + ci8;
    dst[base] = h;
    dst[base + 4608] = l;
}
__global__ void wsplit_all_kernel(const float* Wd1, const float* Wc1, const float* Wd2,
                                  const float* Wc2, const float* Wd3, const float* Wc3,
                                  const float* Wo,
                                  unsigned short* pD1, unsigned short* pC1,
                                  unsigned short* pD2, unsigned short* pC2,
                                  unsigned short* pD3, unsigned short* pC3,
                                  float* pO) {
    int gb = blockIdx.x, tid = threadIdx.x;
    if      (gb < 2304) wsplit_deconv_one(Wd1, pD1, 256, 256, gb * 256 + tid);
    else if (gb < 4608) wsplit_conv_one  (Wc1, pC1, 256, (gb - 2304) * 256 + tid);
    else if (gb < 5760) wsplit_deconv_one(Wd2, pD2, 256, 128, (gb - 4608) * 256 + tid);
    else if (gb < 6336) wsplit_conv_one  (Wc2, pC2, 128, (gb - 5760) * 256 + tid);
    else if (gb < 6912) wsplit_deconv_one(Wd3, pD3, 128, 128, (gb - 6336) * 256 + tid);
    else if (gb < 7488) wsplit_conv_one  (Wc3, pC3, 128, (gb - 6912) * 256 + tid);
    else {
        int idx = (gb - 7488) * 256 + tid;           // Wo[3][128][9] -> pO[3][9][128]
        if (idx < 3456) {
            int co = idx / 1152, r = idx % 1152, ci = r / 9, t = r % 9;
            pO[(co * 9 + t) * 128 + ci] = Wo[(co * 128 + ci) * 9 + t];
        }
    }
}

// ---------------- MFMA conv3x3 (split-bf16 3-term, async reg-staged) --------
// OUTM 1: A-format hi/lo + ReLU. OUTM 2: hi-only. Coalesced cell epilogue.
template<int CIN, int COUT, int H, int W, int P, int OUTM, int NCG>
__global__ __launch_bounds__(256) void convM(const unsigned short* __restrict__ xA,
                                             const unsigned short* __restrict__ wsp,
                                             const float* __restrict__ bias,
                                             unsigned short* __restrict__ outU) {
    constexpr int R = 4 * P;
    constexpr int CH = CIN / 16;
    constexpr size_t LIN = (size_t)H * W * CIN;
    constexpr size_t LOUT = (size_t)H * W * COUT;
    constexpr int NXU = (R + 2) * 34 * 4;
    constexpr int NLX = (NXU + 255) / 256;
    constexpr int NWU = 1152;
    constexpr int NLW = (NCG * NWU + 255) / 256;
    __shared__ __align__(16) unsigned short sX[2][2][R + 2][34][8];
    __shared__ __align__(16) unsigned short sW[NCG][2][2][9][32][8];
    const int tid = threadIdx.x;
    const int lane = tid & 63, wv = tid >> 6;
    const int n = lane & 31, kh = lane >> 5;
    const int x0 = blockIdx.x * 32;
    const int y0 = blockIdx.y * R;
    const int cgb = blockIdx.z;
    const uint4* wU4 = (const uint4*)wsp;

    f32x16 acc[P][NCG];
    #pragma unroll
    for (int p = 0; p < P; ++p)
        #pragma unroll
        for (int cg = 0; cg < NCG; ++cg) acc[p][cg] = (f32x16)0.0f;

    uint4 vx[NLX], vw[NLW];
    auto LOADS = [&](int ch) {
        #pragma unroll
        for (int i = 0; i < NLX; ++i) {
            int idx = tid + i * 256;
            int sub = idx & 3, hl = sub >> 1, khs = sub & 1;
            int cell = idx >> 2, row = cell / 34, col = cell - row * 34;
            int gy = y0 - 1 + row, gx = x0 - 1 + col;
            uint4 v = make_uint4(0u, 0u, 0u, 0u);
            if (idx < NXU && gy >= 0 && gy < H && gx >= 0 && gx < W)
                v = *(const uint4*)&xA[(size_t)hl * LIN +
                        ((size_t)(ch * H + gy) * W + gx) * 16 + khs * 8];
            vx[i] = v;
        }
        #pragma unroll
        for (int i = 0; i < NLW; ++i) {
            int idx = tid + i * 256;
            int idc = (idx < NCG * NWU) ? idx : (NCG * NWU - 1);
            int cg = idc / NWU, j = idc - cg * NWU;
            vw[i] = wU4[(size_t)((cgb * NCG + cg) * CH + ch) * NWU + j];
        }
    };
    auto WRITE = [&]() {
        #pragma unroll
        for (int i = 0; i < NLX; ++i) {
            int idx = tid + i * 256;
            if (idx < NXU) {
                int sub = idx & 3, hl = sub >> 1, khs = sub & 1;
                int cell = idx >> 2, row = cell / 34, col = cell - row * 34;
                *(uint4*)&sX[hl][khs][row][col][0] = vx[i];
            }
        }
        uint4* dW = (uint4*)&sW[0][0][0][0][0][0];
        #pragma unroll
        for (int i = 0; i < NLW; ++i) {
            int idx = tid + i * 256;
            if (idx < NCG * NWU) dW[idx] = vw[i];
        }
    };

    LOADS(0);
    for (int ch = 0; ch < CH; ++ch) {
        __syncthreads();
        WRITE();
        __syncthreads();
        if (ch + 1 < CH) LOADS(ch + 1);
        #pragma unroll
        for (int t = 0; t < 9; ++t) {
            const int ky = t / 3, kx = t % 3;
            short8 w_h[NCG], w_l[NCG];
            #pragma unroll
            for (int cg = 0; cg < NCG; ++cg) {
                w_h[cg] = *(const short8*)&sW[cg][0][kh][t][n][0];
                w_l[cg] = *(const short8*)&sW[cg][1][kh][t][n][0];
            }
            #pragma unroll
            for (int p = 0; p < P; ++p) {
                const int row = wv * P + p + ky;
                short8 xh = *(const short8*)&sX[0][kh][row][n + kx][0];
                short8 xl = *(const short8*)&sX[1][kh][row][n + kx][0];
                #pragma unroll
                for (int cg = 0; cg < NCG; ++cg) {
                    acc[p][cg] = __builtin_amdgcn_mfma_f32_32x32x16_bf16(w_h[cg], xh, acc[p][cg], 0, 0, 0);
                    acc[p][cg] = __builtin_amdgcn_mfma_f32_32x32x16_bf16(w_h[cg], xl, acc[p][cg], 0, 0, 0);
                    acc[p][cg] = __builtin_amdgcn_mfma_f32_32x32x16_bf16(w_l[cg], xh, acc[p][cg], 0, 0, 0);
                }
            }
        }
    }
    // ---- coalesced epilogue: full 32B cells via half-wave exchange ----
    // kh=0 owns cell words {0,1,4,5}, kh=1 owns {2,3,6,7} (C/D layout).
    #pragma unroll
    for (int p = 0; p < P; ++p) {
        const int y = y0 + wv * P + p;
        #pragma unroll
        for (int cg = 0; cg < NCG; ++cg) {
            const int coBase = (cgb * NCG + cg) * 32;
            float v[16];
            #pragma unroll
            for (int reg = 0; reg < 16; ++reg) {
                int col = (reg & 3) + 8 * (reg >> 2) + 4 * kh;
                v[reg] = fmaxf(acc[p][cg][reg] + bias[coBase + col], 0.f);
            }
            uint32_t Ah[4], Bh[4], Al[4], Bl[4];
            #pragma unroll
            for (int k = 0; k < 4; ++k) {
                Ah[k] = pack2(v[2 * k], v[2 * k + 1]);
                Bh[k] = pack2(v[8 + 2 * k], v[9 + 2 * k]);
                if constexpr (OUTM == 1) {
                    float a0 = v[2 * k] - bf2f(f2bf(v[2 * k]));
                    float a1 = v[2 * k + 1] - bf2f(f2bf(v[2 * k + 1]));
                    float b0 = v[8 + 2 * k] - bf2f(f2bf(v[8 + 2 * k]));
                    float b1 = v[9 + 2 * k] - bf2f(f2bf(v[9 + 2 * k]));
                    Al[k] = pack2(a0, a1);
                    Bl[k] = pack2(b0, b1);
                }
            }
            uint32_t rh[4], rl[4];
            #pragma unroll
            for (int k = 0; k < 4; ++k)
                rh[k] = (uint32_t)__shfl_xor((int)(kh ? Ah[k] : Bh[k]), 32, 64);
            if constexpr (OUTM == 1) {
                #pragma unroll
                for (int k = 0; k < 4; ++k)
                    rl[k] = (uint32_t)__shfl_xor((int)(kh ? Al[k] : Bl[k]), 32, 64);
            }
            const int cell = (coBase >> 4) + kh;
            size_t aoff = ((size_t)cell * H * W + (size_t)y * W + (x0 + n)) * 16;
            uint4 lo16, hi16;
            if (kh == 0) {
                lo16 = make_uint4(Ah[0], Ah[1], rh[0], rh[1]);
                hi16 = make_uint4(Ah[2], Ah[3], rh[2], rh[3]);
            } else {
                lo16 = make_uint4(rh[0], rh[1], Bh[0], Bh[1]);
                hi16 = make_uint4(rh[2], rh[3], Bh[2], Bh[3]);
            }
            *(uint4*)&outU[aoff] = lo16;
            *(uint4*)&outU[aoff + 8] = hi16;
            if constexpr (OUTM == 1) {
                uint4 lo16l, hi16l;
                if (kh == 0) {
                    lo16l = make_uint4(Al[0], Al[1], rl[0], rl[1]);
                    hi16l = make_uint4(Al[2], Al[3], rl[2], rl[3]);
                } else {
                    lo16l = make_uint4(rl[0], rl[1], Bl[0], Bl[1]);
                    hi16l = make_uint4(rl[2], rl[3], Bl[2], Bl[3]);
                }
                *(uint4*)&outU[aoff + LOUT] = lo16l;
                *(uint4*)&outU[aoff + LOUT + 8] = hi16l;
            }
        }
    }
}

// ---------------- MFMA deconv (parity-split, async reg-staged) --------------
template<int CIN, int COUT, int HIN, int WIN>
__global__ __launch_bounds__(256) void deconvM(const unsigned short* __restrict__ xA,
                                               const unsigned short* __restrict__ wsp,
                                               const float* __restrict__ bias,
                                               unsigned short* __restrict__ outA) {
    constexpr int HO = 2 * HIN, WO = 2 * WIN;
    constexpr int CH = CIN / 16;
    constexpr size_t LIN = (size_t)HIN * WIN * CIN;
    constexpr size_t LOUT = (size_t)HO * WO * COUT;
    constexpr int NXU = 5 * 33 * 4;
    constexpr int NLX = (NXU + 255) / 256;
    constexpr int NWU = 1152;
    constexpr int NLW = (NWU + 255) / 256;
    __shared__ __align__(16) unsigned short sX[2][2][5][33][8];
    __shared__ __align__(16) unsigned short sW[2][2][9][32][8];
    const int tid = threadIdx.x;
    const int lane = tid & 63, wv = tid >> 6;
    const int n = lane & 31, kh = lane >> 5;
    const int x0 = blockIdx.x * 32;
    const int y0q = blockIdx.y * 4;
    const int cog = blockIdx.z;
    const uint4* wU4 = (const uint4*)wsp;

    f32x16 acc[4];
    #pragma unroll
    for (int d = 0; d < 4; ++d) acc[d] = (f32x16)0.0f;

    uint4 vx[NLX], vw[NLW];
    auto LOADS = [&](int ch) {
        #pragma unroll
        for (int i = 0; i < NLX; ++i) {
            int idx = tid + i * 256;
            int sub = idx & 3, hl = sub >> 1, khs = sub & 1;
            int cell = idx >> 2, row = cell / 33, col = cell - row * 33;
            int gy = y0q + row, gx = x0 + col;
            uint4 v = make_uint4(0u, 0u, 0u, 0u);
            if (idx < NXU && gy < HIN && gx < WIN)
                v = *(const uint4*)&xA[(size_t)hl * LIN +
                        ((size_t)(ch * HIN + gy) * WIN + gx) * 16 + khs * 8];
            vx[i] = v;
        }
        #pragma unroll
        for (int i = 0; i < NLW; ++i) {
            int idx = tid + i * 256;
            int idc = (idx < NWU) ? idx : (NWU - 1);
            vw[i] = wU4[(size_t)(cog * CH + ch) * NWU + idc];
        }
    };
    auto WRITE = [&]() {
        #pragma unroll
        for (int i = 0; i < NLX; ++i) {
            int idx = tid + i * 256;
            if (idx < NXU) {
                int sub = idx & 3, hl = sub >> 1, khs = sub & 1;
                int cell = idx >> 2, row = cell / 33, col = cell - row * 33;
                *(uint4*)&sX[hl][khs][row][col][0] = vx[i];
            }
        }
        uint4* dW = (uint4*)&sW[0][0][0][0][0];
        #pragma unroll
        for (int i = 0; i < NLW; ++i) {
            int idx = tid + i * 256;
            if (idx < NWU) dW[idx] = vw[i];
        }
    };

    LOADS(0);
    for (int ch = 0; ch < CH; ++ch) {
        __syncthreads();
        WRITE();
        __syncthreads();
        if (ch + 1 < CH) LOADS(ch + 1);
        short8 xf[2][2][2];     // [hl][dy][dx]
        #pragma unroll
        for (int dy = 0; dy < 2; ++dy)
            #pragma unroll
            for (int dx = 0; dx < 2; ++dx) {
                xf[0][dy][dx] = *(const short8*)&sX[0][kh][wv + dy][n + dx][0];
                xf[1][dy][dx] = *(const short8*)&sX[1][kh][wv + dy][n + dx][0];
            }
        constexpr int SRC[9] = {3, 2, 2, 1, 0, 0, 1, 0, 0};
        constexpr int DST[9] = {3, 2, 3, 1, 0, 1, 3, 2, 3};
        #pragma unroll
        for (int t = 0; t < 9; ++t) {
            short8 wh = *(const short8*)&sW[0][kh][t][n][0];
            short8 wl = *(const short8*)&sW[1][kh][t][n][0];
            const int dy = SRC[t] >> 1, dx = SRC[t] & 1, d = DST[t];
            acc[d] = __builtin_amdgcn_mfma_f32_32x32x16_bf16(wh, xf[0][dy][dx], acc[d], 0, 0, 0);
            acc[d] = __builtin_amdgcn_mfma_f32_32x32x16_bf16(wh, xf[1][dy][dx], acc[d], 0, 0, 0);
            acc[d] = __builtin_amdgcn_mfma_f32_32x32x16_bf16(wl, xf[0][dy][dx], acc[d], 0, 0, 0);
        }
    }
    // ---- coalesced epilogue: per quad-row, lane writes 64B contiguous ----
    const int oyb = 2 * (y0q + wv);
    const int cell = cog * 2 + kh;
    #pragma unroll
    for (int py = 0; py < 2; ++py) {
        const int oy = oyb + py;
        uint4 cellw[2][2], celll[2][2];          // [px][half16]
        #pragma unroll
        for (int px = 0; px < 2; ++px) {
            const int pos = py * 2 + px;
            float v[16];
            #pragma unroll
            for (int reg = 0; reg < 16; ++reg) {
                int col = (reg & 3) + 8 * (reg >> 2) + 4 * kh;
                v[reg] = fmaxf(acc[pos][reg] + bias[cog * 32 + col], 0.f);
            }
            uint32_t Ah[4], Bh[4], Al[4], Bl[4];
            #pragma unroll
            for (int k = 0; k < 4; ++k) {
                Ah[k] = pack2(v[2 * k], v[2 * k + 1]);
                Bh[k] = pack2(v[8 + 2 * k], v[9 + 2 * k]);
                Al[k] = pack2(v[2 * k] - bf2f(f2bf(v[2 * k])),
                              v[2 * k + 1] - bf2f(f2bf(v[2 * k + 1])));
                Bl[k] = pack2(v[8 + 2 * k] - bf2f(f2bf(v[8 + 2 * k])),
                              v[9 + 2 * k] - bf2f(f2bf(v[9 + 2 * k])));
            }
            uint32_t rh[4], rl[4];
            #pragma unroll
            for (int k = 0; k < 4; ++k) {
                rh[k] = (uint32_t)__shfl_xor((int)(kh ? Ah[k] : Bh[k]), 32, 64);
                rl[k] = (uint32_t)__shfl_xor((int)(kh ? Al[k] : Bl[k]), 32, 64);
            }
            if (kh == 0) {
                cellw[px][0] = make_uint4(Ah[0], Ah[1], rh[0], rh[1]);
                cellw[px][1] = make_uint4(Ah[2], Ah[3], rh[2], rh[3]);
                celll[px][0] = make_uint4(Al[0], Al[1], rl[0], rl[1]);
                celll[px][1] = make_uint4(Al[2], Al[3], rl[2], rl[3]);
            } else {
                cellw[px][0] = make_uint4(rh[0], rh[1], Bh[0], Bh[1]);
                cellw[px][1] = make_uint4(rh[2], rh[3], Bh[2], Bh[3]);
                celll[px][0] = make_uint4(rl[0], rl[1], Bl[0], Bl[1]);
                celll[px][1] = make_uint4(rl[2], rl[3], Bl[2], Bl[3]);
            }
        }
        // lane writes 64B contiguous (px=0 cell then px=1 cell)
        size_t aoff = ((size_t)cell * HO * WO + (size_t)oy * WO + 2 * (x0 + n)) * 16;
        *(uint4*)&outA[aoff]      = cellw[0][0];
        *(uint4*)&outA[aoff + 8]  = cellw[0][1];
        *(uint4*)&outA[aoff + 16] = cellw[1][0];
        *(uint4*)&outA[aoff + 24] = cellw[1][1];
        *(uint4*)&outA[aoff + LOUT]      = celll[0][0];
        *(uint4*)&outA[aoff + LOUT + 8]  = celll[0][1];
        *(uint4*)&outA[aoff + LOUT + 16] = celll[1][0];
        *(uint4*)&outA[aoff + LOUT + 24] = celll[1][1];
    }
}

// ---------------- final conv (128->3) + tanh, from bf16-hi A-format ----------
__global__ __launch_bounds__(256) void coA_kernel(const unsigned short* __restrict__ xA,
                                                  const float* __restrict__ wO,
                                                  const float* __restrict__ bo,
                                                  float* __restrict__ rec) {
    const int tid = threadIdx.x;
    const int lx = tid & 15, ly = tid >> 4;
    const int tx0 = (blockIdx.x & 15) * 16, ty0 = (blockIdx.x >> 4) * 16;
    const int ox = tx0 + lx, oy = ty0 + ly;
    float a0 = bo[0], a1 = bo[1], a2 = bo[2];
    for (int ch = 0; ch < 8; ++ch) {
        unsigned short cs[9][16];
        #pragma unroll
        for (int t = 0; t < 9; ++t) {
            const int gy = oy - 1 + t / 3, gx = ox - 1 + t % 3;
            uint4 v0 = make_uint4(0u, 0u, 0u, 0u), v1 = make_uint4(0u, 0u, 0u, 0u);
            if (gy >= 0 && gy < 256 && gx >= 0 && gx < 256) {
                const uint4* p = (const uint4*)&xA[((size_t)(ch * 256 + gy) * 256 + gx) * 16];
                v0 = p[0]; v1 = p[1];
            }
            *(uint4*)&cs[t][0] = v0;
            *(uint4*)&cs[t][8] = v1;
        }
        #pragma unroll
        for (int t = 0; t < 9; ++t) {
            const float* w0 = &wO[(0 * 9 + t) * 128 + ch * 16];
            const float* w1 = &wO[(1 * 9 + t) * 128 + ch * 16];
            const float* w2 = &wO[(2 * 9 + t) * 128 + ch * 16];
            #pragma unroll
            for (int j = 0; j < 16; ++j) {
                float v = bf2f(cs[t][j]);
                a0 = fmaf(v, w0[j], a0);
                a1 = fmaf(v, w1[j], a1);
                a2 = fmaf(v, w2[j], a2);
            }
        }
    }
    const int px = oy * 256 + ox;
    rec[px]                = tanhf(a0);
    rec[65536 + px]        = tanhf(a1);
    rec[2 * 65536 + px]    = tanhf(a2);
}

// ---------------------------------------------------------------------------
extern "C" void kernel_launch(void* const* d_in, const int* in_sizes, int n_in,
                              void* d_out, int out_size, void* d_ws, size_t ws_size,
                              hipStream_t stream) {
    const float* x   = (const float*)d_in[0];
    const float* We0 = (const float*)d_in[1];  const float* be0 = (const float*)d_in[2];
    const float* We1 = (const float*)d_in[3];  const float* be1 = (const float*)d_in[4];
    const float* Wi  = (const float*)d_in[5];  const float* bi  = (const float*)d_in[6];
    const float* Wd1 = (const float*)d_in[7];  const float* bd1 = (const float*)d_in[8];
    const float* Wc1 = (const float*)d_in[9];  const float* bc1 = (const float*)d_in[10];
    const float* Wd2 = (const float*)d_in[11]; const float* bd2 = (const float*)d_in[12];
    const float* Wc2 = (const float*)d_in[13]; const float* bc2 = (const float*)d_in[14];
    const float* Wd3 = (const float*)d_in[15]; const float* bd3 = (const float*)d_in[16];
    const float* Wc3 = (const float*)d_in[17]; const float* bc3 = (const float*)d_in[18];
    const float* Wo  = (const float*)d_in[19]; const float* bo  = (const float*)d_in[20];

    float* out    = (float*)d_out;
    float* rec    = out;               // [8,3,256,256]
    float* routed = out + 1572864;     // [8,4,32,32]
    float* grain  = out + 1605632;     // [8,16,16]
    float* ent    = out + 1607680;     // [8,16,16]

    // latent scratch in rec region (dead before first rec write)
    float* latf = out;                 // 32768 floats
    float* latc = out + 32768;         // 8192 floats
    float* thr  = out + 40960;         // 1 float
    unsigned short* slotC3 = (unsigned short*)(out + 1425408);

    // workspace: U activations [0,16.8M); slots [24M,32M); V = [32M,65.6M).
    char* ws8 = (char*)d_ws;
    unsigned short* Uu    = (unsigned short*)ws8;
    unsigned short* Vp    = (unsigned short*)(ws8 + (size_t)32 * 1024 * 1024);
    unsigned short* wspD1 = (unsigned short*)(ws8 + (size_t)24 * 1024 * 1024);
    unsigned short* wspC1 = (unsigned short*)(ws8 + (size_t)26 * 1024 * 1024 + 512 * 1024);
    unsigned short* wspD2 = (unsigned short*)(ws8 + (size_t)29 * 1024 * 1024);
    unsigned short* wspD3 = (unsigned short*)(ws8 + (size_t)30 * 1024 * 1024 + 256 * 1024);
    unsigned short* wspC2 = (unsigned short*)(ws8 + (size_t)31 * 1024 * 1024);
    float*          wspO  = (float*)(ws8 + (size_t)31 * 1024 * 1024 + 768 * 1024);

    // --- entropy / routing path ---
    enc_conv_kernel<<<128, 256, 0, stream>>>(x, We0, be0, latf, 8, 32);
    enc_conv_kernel<<<32, 256, 0, stream>>>(x, We1, be1, latc, 16, 16);
    entropy_kernel<<<2048, 256, 0, stream>>>(x, ent);
    median_kernel<<<1, 1024, 0, stream>>>(ent, thr);
    grain_kernel<<<8, 256, 0, stream>>>(ent, thr, grain);
    route_kernel<<<128, 256, 0, stream>>>(latf, latc, grain, routed);

    // --- weight pre-split: ONCE ---
    wsplit_all_kernel<<<7502, 256, 0, stream>>>(Wd1, Wc1, Wd2, Wc2, Wd3, Wc3, Wo,
                                                wspD1, wspC1, wspD2, wspC2, wspD3, slotC3,
                                                wspO);

    // --- decoder, per batch ---
    for (int b = 0; b < B; ++b) {
        const float* rb = routed + (size_t)b * 4 * 32 * 32;
        float* recb = rec + (size_t)b * 3 * 65536;
        conv3x3A<4, 256, 32, 32, 4, 16><<<dim3(16, 4, 1), 256, 0, stream>>>(rb, Wi, bi, Uu);
        deconvM<256, 256, 32, 32><<<dim3(1, 8, 8), 256, 0, stream>>>(Uu, wspD1, bd1, Vp);
        convM<256, 256, 64, 64, 1, 1, 1><<<dim3(2, 16, 8), 256, 0, stream>>>(Vp, wspC1, bc1, Uu);
        deconvM<256, 128, 64, 64><<<dim3(2, 16, 4), 256, 0, stream>>>(Uu, wspD2, bd2, Vp);
        convM<128, 128, 128, 128, 1, 1, 1><<<dim3(4, 32, 4), 256, 0, stream>>>(Vp, wspC2, bc2, Uu);
        deconvM<128, 128, 128, 128><<<dim3(4, 32, 4), 256, 0, stream>>>(Uu, wspD3, bd3, Vp);
        convM<128, 128, 256, 256, 2, 2, 2><<<dim3(8, 32, 2), 256, 0, stream>>>(Vp, slotC3, bc3, Uu);
        coA_kernel<<<256, 256, 0, stream>>>(Uu, wspO, bo, recb);
    }
}

// Round 10
// 1885.778 us; speedup vs baseline: 1.4261x; 1.4261x over previous
//
#include <hip/hip_runtime.h>
#include <hip/hip_bf16.h>
#include <cstdint>
#include <cstddef>

// ---------------------------------------------------------------------------
// DVAE forward v9: spill elimination in convM/deconvM.
// Round-9 diagnosis: WRITE_SIZE 157MB vs 16.8MB output with clean FETCH and
// identical values across two epilogue variants => scratch spill traffic from
// the register-resident prefetch (static liveness ~139 VGPR > allocated 116).
// Fix: (1) weights staged via __builtin_amdgcn_global_load_lds into a
// double-buffered LDS region (no VGPR transit, -36 regs); DMA for ch+1 issued
// after the post-write barrier -> latency hides under compute(ch); next
// loop-top __syncthreads drains it. (2) convM NCG fixed at 1 (acc 64->32).
// (3) deconvM compute split by hi/lo fragment (xf liveness 32->16).
// Budgets now ~100 (convM) / ~110 (deconvM) VGPRs -> no spill.
// ---------------------------------------------------------------------------

#define B 8

typedef __attribute__((ext_vector_type(8)))  short  short8;
typedef __attribute__((ext_vector_type(4)))  short  short4v;
typedef __attribute__((ext_vector_type(16))) float  f32x16;

__device__ inline unsigned short f2bf(float x) {          // RNE f32->bf16
    uint32_t u = __float_as_uint(x);
    uint32_t r = (u + 0x7FFFu + ((u >> 16) & 1u)) >> 16;
    return (unsigned short)r;
}
__device__ inline float bf2f(unsigned short h) {
    return __uint_as_float(((uint32_t)h) << 16);
}
__device__ inline uint32_t pack2(float a, float b) {
    return (uint32_t)f2bf(a) | ((uint32_t)f2bf(b) << 16);
}

typedef __attribute__((address_space(3))) void lds_void;
typedef const __attribute__((address_space(1))) void gbl_void;
__device__ inline void gll16(const void* g, void* l) {
    __builtin_amdgcn_global_load_lds((gbl_void*)g, (lds_void*)l, 16, 0, 0);
}

// ---------------- encoder strided conv (Cin=3, Cout=4, k=3, pad=1) ----------
__global__ void enc_conv_kernel(const float* __restrict__ x, const float* __restrict__ w,
                                const float* __restrict__ bias, float* __restrict__ out,
                                int S, int HO) {
    int id = blockIdx.x * 256 + threadIdx.x;
    int total = B * 4 * HO * HO;
    if (id >= total) return;
    int ox = id % HO, oy = (id / HO) % HO, co = (id / (HO * HO)) % 4, b = id / (HO * HO * 4);
    float acc = bias[co];
    for (int ci = 0; ci < 3; ++ci) {
        const float* xp = x + ((size_t)b * 3 + ci) * 65536;
        const float* wp = w + (co * 3 + ci) * 9;
        #pragma unroll
        for (int ky = 0; ky < 3; ++ky) {
            int iy = oy * S - 1 + ky;
            if (iy < 0 || iy >= 256) continue;
            #pragma unroll
            for (int kx = 0; kx < 3; ++kx) {
                int ix = ox * S - 1 + kx;
                if (ix < 0 || ix >= 256) continue;
                acc = fmaf(xp[iy * 256 + ix], wp[ky * 3 + kx], acc);
            }
        }
    }
    out[id] = acc;
}

// ---------------- entropy (KDE), gray fused ----------------
__global__ __launch_bounds__(256) void entropy_kernel(const float* __restrict__ x,
                                                      float* __restrict__ ent) {
    __shared__ float s_patch[256];
    __shared__ float s_red[4];
    int blk = blockIdx.x;
    int b = blk >> 8, rem = blk & 255;
    int py = rem >> 4, px = rem & 15;
    int tid = threadIdx.x;
    int pr = tid >> 4, pc = tid & 15;
    const float* xb = x + (size_t)b * 3 * 65536;
    int p = (py * 16 + pr) * 256 + (px * 16 + pc);
    s_patch[tid] = 0.299f * xb[p] + 0.587f * xb[65536 + p] + 0.114f * xb[2 * 65536 + p];
    __syncthreads();

    float bin = (float)tid * (1.0f / 255.0f);
    float s = 0.f;
    #pragma unroll 8
    for (int q = 0; q < 256; ++q) {
        float t = (s_patch[q] - bin) * 100.0f;
        s += expf(-0.5f * (t * t));
    }
    float pdf = s * (1.0f / 256.0f);

    float r = pdf;
    #pragma unroll
    for (int o = 32; o > 0; o >>= 1) r += __shfl_down(r, o, 64);
    if ((tid & 63) == 0) s_red[tid >> 6] = r;
    __syncthreads();
    float total = s_red[0] + s_red[1] + s_red[2] + s_red[3];
    __syncthreads();

    float p2 = pdf / total;
    p2 = fmaxf(p2, 1e-10f);
    float e = -p2 * log2f(p2);
    #pragma unroll
    for (int o = 32; o > 0; o >>= 1) e += __shfl_down(e, o, 64);
    if ((tid & 63) == 0) s_red[tid >> 6] = e;
    __syncthreads();
    if (tid == 0) ent[blk] = s_red[0] + s_red[1] + s_red[2] + s_red[3];
}

// ---------------- median of 2048 values (bitonic sort) ----------------
__global__ __launch_bounds__(1024) void median_kernel(const float* __restrict__ ent,
                                                      float* __restrict__ thr) {
    __shared__ float s[2048];
    int tid = threadIdx.x;
    s[tid] = ent[tid];
    s[tid + 1024] = ent[tid + 1024];
    __syncthreads();
    for (int k = 2; k <= 2048; k <<= 1) {
        for (int j = k >> 1; j > 0; j >>= 1) {
            int t = tid;
            #pragma unroll 1
            for (int rep = 0; rep < 2; ++rep, t += 1024) {
                int ixj = t ^ j;
                if (ixj > t) {
                    float a = s[t], bb = s[ixj];
                    bool up = ((t & k) == 0);
                    bool sw = up ? (a > bb) : (a < bb);
                    if (sw) { s[t] = bb; s[ixj] = a; }
                }
            }
            __syncthreads();
        }
    }
    if (tid == 0) *thr = 0.5f * (s[1023] + s[1024]);
}

__global__ void grain_kernel(const float* __restrict__ ent, const float* __restrict__ thr,
                             float* __restrict__ grain) {
    int id = blockIdx.x * 256 + threadIdx.x;
    if (id >= 2048) return;
    grain[id] = (ent[id] > *thr) ? 1.0f : 0.0f;
}

__global__ void route_kernel(const float* __restrict__ latf, const float* __restrict__ latc,
                             const float* __restrict__ grain, float* __restrict__ routed) {
    int id = blockIdx.x * 256 + threadIdx.x;
    if (id >= B * 4 * 32 * 32) return;
    int xx = id & 31, yy = (id >> 5) & 31, c = (id >> 10) & 3, b = id >> 12;
    float g = grain[b * 256 + (yy >> 1) * 16 + (xx >> 1)];
    float cu = latc[((b * 4 + c) * 16 + (yy >> 1)) * 16 + (xx >> 1)];
    routed[id] = g * latf[id] + (1.0f - g) * cu;
}

// ---------------- fp32 conv3x3 (Wi -> A-format) ----------------
template<int CIN, int COUT, int H, int W, int CI_BLK, int CO_BLK>
__global__ __launch_bounds__(256) void conv3x3A(const float* __restrict__ in,
                                                const float* __restrict__ wgt,
                                                const float* __restrict__ bias,
                                                unsigned short* __restrict__ outA) {
    constexpr int TW = W / 16;
    __shared__ float s_in[CI_BLK][18][18];
    __shared__ float s_w[CI_BLK][9][CO_BLK];
    const int tid = threadIdx.x;
    const int lx = tid & 15, ly = tid >> 4;
    const int co0 = blockIdx.x * CO_BLK;
    const int tile = blockIdx.y;
    const int tx0 = (tile % TW) * 16, ty0 = (tile / TW) * 16;
    const int ox = tx0 + lx, oy = ty0 + ly;

    float acc[CO_BLK];
    #pragma unroll
    for (int i = 0; i < CO_BLK; ++i) acc[i] = bias[co0 + i];

    for (int ci0 = 0; ci0 < CIN; ci0 += CI_BLK) {
        for (int idx = tid; idx < CI_BLK * 324; idx += 256) {
            int ci = idx / 324, rm = idx % 324;
            int r = rm / 18, c = rm % 18;
            int iy = ty0 - 1 + r, ix = tx0 - 1 + c;
            float v = 0.f;
            if (iy >= 0 && iy < H && ix >= 0 && ix < W)
                v = in[((size_t)(ci0 + ci) * H + iy) * W + ix];
            s_in[ci][r][c] = v;
        }
        for (int idx = tid; idx < CI_BLK * 9 * CO_BLK; idx += 256) {
            int ci = idx / (9 * CO_BLK), rm = idx % (9 * CO_BLK);
            int k = rm / CO_BLK, co = rm % CO_BLK;
            s_w[ci][k][co] = wgt[((size_t)(co0 + co) * CIN + ci0 + ci) * 9 + k];
        }
        __syncthreads();
        #pragma unroll
        for (int ci = 0; ci < CI_BLK; ++ci) {
            float v[9];
            #pragma unroll
            for (int ky = 0; ky < 3; ++ky)
                #pragma unroll
                for (int kx = 0; kx < 3; ++kx)
                    v[ky * 3 + kx] = s_in[ci][ly + ky][lx + kx];
            #pragma unroll
            for (int k = 0; k < 9; ++k) {
                #pragma unroll
                for (int c4 = 0; c4 < CO_BLK / 4; ++c4) {
                    const float4 w4 = *reinterpret_cast<const float4*>(&s_w[ci][k][c4 * 4]);
                    acc[c4 * 4 + 0] = fmaf(v[k], w4.x, acc[c4 * 4 + 0]);
                    acc[c4 * 4 + 1] = fmaf(v[k], w4.y, acc[c4 * 4 + 1]);
                    acc[c4 * 4 + 2] = fmaf(v[k], w4.z, acc[c4 * 4 + 2]);
                    acc[c4 * 4 + 3] = fmaf(v[k], w4.w, acc[c4 * 4 + 3]);
                }
            }
        }
        __syncthreads();
    }
    #pragma unroll
    for (int co = 0; co < CO_BLK; ++co) {
        float v = acc[co];
        int c = co0 + co;
        unsigned short h = f2bf(v);
        unsigned short l = f2bf(v - bf2f(h));
        size_t a = ((size_t)(c >> 4) * H * W + (size_t)oy * W + ox) * 16 + (c & 15);
        outA[a] = h;
        outA[a + (size_t)H * W * COUT] = l;
    }
}

// ---------------- fused weight pre-split (runs ONCE) ------------------------
// unified slot layout (conv AND deconv): [cob32][ch][hl][kh][t][co32][ci8]
__device__ inline void wsplit_conv_one(const float* __restrict__ w, unsigned short* dst,
                                       int CIN, int idx) {
    int t = idx % 9;
    int ci = (idx / 9) % CIN;
    int co = idx / (9 * CIN);
    float x = w[idx];                   // w[co][ci][t]
    unsigned short h = f2bf(x);
    unsigned short l = f2bf(x - bf2f(h));
    int CH = CIN >> 4;
    int cob = co >> 5, col = co & 31;
    int ch = ci >> 4, kh = (ci >> 3) & 1, ci8 = ci & 7;
    size_t base = (size_t)(cob * CH + ch) * 9216 + (size_t)((kh * 9 + t) * 256) + col * 8 + ci8;
    dst[base] = h;
    dst[base + 4608] = l;
}
__device__ inline void wsplit_deconv_one(const float* __restrict__ w, unsigned short* dst,
                                         int CIN, int COUT, int idx) {
    int t = idx % 9;
    int co = (idx / 9) % COUT;
    int ci = idx / (9 * COUT);
    float x = w[idx];                   // w[ci][co][t]
    unsigned short h = f2bf(x);
    unsigned short l = f2bf(x - bf2f(h));
    int CH = CIN >> 4;
    int cob = co >> 5, col = co & 31;
    int ch = ci >> 4, kh = (ci >> 3) & 1, ci8 = ci & 7;
    size_t base = (size_t)(cob * CH + ch) * 9216 + (size_t)((kh * 9 + t) * 256) + col * 8 + ci8;
    dst[base] = h;
    dst[base + 4608] = l;
}
__global__ void wsplit_all_kernel(const float* Wd1, const float* Wc1, const float* Wd2,
                                  const float* Wc2, const float* Wd3, const float* Wc3,
                                  const float* Wo,
                                  unsigned short* pD1, unsigned short* pC1,
                                  unsigned short* pD2, unsigned short* pC2,
                                  unsigned short* pD3, unsigned short* pC3,
                                  float* pO) {
    int gb = blockIdx.x, tid = threadIdx.x;
    if      (gb < 2304) wsplit_deconv_one(Wd1, pD1, 256, 256, gb * 256 + tid);
    else if (gb < 4608) wsplit_conv_one  (Wc1, pC1, 256, (gb - 2304) * 256 + tid);
    else if (gb < 5760) wsplit_deconv_one(Wd2, pD2, 256, 128, (gb - 4608) * 256 + tid);
    else if (gb < 6336) wsplit_conv_one  (Wc2, pC2, 128, (gb - 5760) * 256 + tid);
    else if (gb < 6912) wsplit_deconv_one(Wd3, pD3, 128, 128, (gb - 6336) * 256 + tid);
    else if (gb < 7488) wsplit_conv_one  (Wc3, pC3, 128, (gb - 6912) * 256 + tid);
    else {
        int idx = (gb - 7488) * 256 + tid;           // Wo[3][128][9] -> pO[3][9][128]
        if (idx < 3456) {
            int co = idx / 1152, r = idx % 1152, ci = r / 9, t = r % 9;
            pO[(co * 9 + t) * 128 + ci] = Wo[(co * 128 + ci) * 9 + t];
        }
    }
}

// ---------------- MFMA conv3x3 (split-bf16, W via LDS-DMA dbuf) -------------
// In: A-format bf16 hi/lo. OUTM 1: A-format hi/lo + ReLU. OUTM 2: hi-only.
// 32 couts per block (blockIdx.z = cob32).
template<int CIN, int COUT, int H, int W, int P, int OUTM>
__global__ __launch_bounds__(256) void convM(const unsigned short* __restrict__ xA,
                                             const unsigned short* __restrict__ wsp,
                                             const float* __restrict__ bias,
                                             unsigned short* __restrict__ outU) {
    constexpr int R = 4 * P;
    constexpr int CH = CIN / 16;
    constexpr size_t LIN = (size_t)H * W * CIN;
    constexpr size_t LOUT = (size_t)H * W * COUT;
    constexpr int NXU = (R + 2) * 34 * 4;
    constexpr int NLX = (NXU + 255) / 256;
    constexpr int NWU = 1152;                       // uint4 per (cob32, ch)
    __shared__ __align__(16) unsigned short sX[2][2][R + 2][34][8];
    __shared__ __align__(16) unsigned short sW[2][2][2][9][32][8];  // [buf][hl][kh][t][co][ci8]
    const int tid = threadIdx.x;
    const int lane = tid & 63, wv = tid >> 6;
    const int n = lane & 31, kh = lane >> 5;
    const int x0 = blockIdx.x * 32;
    const int y0 = blockIdx.y * R;
    const int cgb = blockIdx.z;
    const uint4* wU4 = (const uint4*)wsp;

    f32x16 acc[P];
    #pragma unroll
    for (int p = 0; p < P; ++p) acc[p] = (f32x16)0.0f;

    uint4 vx[NLX];
    auto LOADSX = [&](int ch) {
        #pragma unroll
        for (int i = 0; i < NLX; ++i) {
            int idx = tid + i * 256;
            int sub = idx & 3, hl = sub >> 1, khs = sub & 1;
            int cell = idx >> 2, row = cell / 34, col = cell - row * 34;
            int gy = y0 - 1 + row, gx = x0 - 1 + col;
            uint4 v = make_uint4(0u, 0u, 0u, 0u);
            if (idx < NXU && gy >= 0 && gy < H && gx >= 0 && gx < W)
                v = *(const uint4*)&xA[(size_t)hl * LIN +
                        ((size_t)(ch * H + gy) * W + gx) * 16 + khs * 8];
            vx[i] = v;
        }
    };
    auto WRITEX = [&]() {
        #pragma unroll
        for (int i = 0; i < NLX; ++i) {
            int idx = tid + i * 256;
            if (idx < NXU) {
                int sub = idx & 3, hl = sub >> 1, khs = sub & 1;
                int cell = idx >> 2, row = cell / 34, col = cell - row * 34;
                *(uint4*)&sX[hl][khs][row][col][0] = vx[i];
            }
        }
    };
    auto GLLW = [&](int buf, int ch) {
        const uint4* src = wU4 + (size_t)(cgb * CH + ch) * NWU;
        uint4* dst = (uint4*)&sW[buf][0][0][0][0][0];
        #pragma unroll
        for (int i = 0; i < (NWU + 255) / 256; ++i) {
            int idx = tid + i * 256;
            if (idx < NWU) gll16(&src[idx], &dst[idx]);   // tail guard is wave-uniform
        }
    };

    LOADSX(0);
    GLLW(0, 0);
    for (int ch = 0; ch < CH; ++ch) {
        const int buf = ch & 1;
        __syncthreads();                 // drains vx(ch) + W-DMA(ch); prev compute done
        WRITEX();
        __syncthreads();                 // sX visible (cheap: nothing global in flight)
        if (ch + 1 < CH) { GLLW(buf ^ 1, ch + 1); LOADSX(ch + 1); }
        #pragma unroll
        for (int t = 0; t < 9; ++t) {
            const int ky = t / 3, kx = t % 3;
            short8 w_h = *(const short8*)&sW[buf][0][kh][t][n][0];
            short8 w_l = *(const short8*)&sW[buf][1][kh][t][n][0];
            #pragma unroll
            for (int p = 0; p < P; ++p) {
                const int row = wv * P + p + ky;
                short8 xh = *(const short8*)&sX[0][kh][row][n + kx][0];
                short8 xl = *(const short8*)&sX[1][kh][row][n + kx][0];
                acc[p] = __builtin_amdgcn_mfma_f32_32x32x16_bf16(w_h, xh, acc[p], 0, 0, 0);
                acc[p] = __builtin_amdgcn_mfma_f32_32x32x16_bf16(w_h, xl, acc[p], 0, 0, 0);
                acc[p] = __builtin_amdgcn_mfma_f32_32x32x16_bf16(w_l, xh, acc[p], 0, 0, 0);
            }
        }
    }
    // ---- coalesced epilogue: full 32B cells via half-wave exchange ----
    const int coBase = cgb * 32;
    #pragma unroll
    for (int p = 0; p < P; ++p) {
        const int y = y0 + wv * P + p;
        float v[16];
        #pragma unroll
        for (int reg = 0; reg < 16; ++reg) {
            int col = (reg & 3) + 8 * (reg >> 2) + 4 * kh;
            v[reg] = fmaxf(acc[p][reg] + bias[coBase + col], 0.f);
        }
        uint32_t Ah[4], Bh[4], Al[4], Bl[4];
        #pragma unroll
        for (int k = 0; k < 4; ++k) {
            Ah[k] = pack2(v[2 * k], v[2 * k + 1]);
            Bh[k] = pack2(v[8 + 2 * k], v[9 + 2 * k]);
            if constexpr (OUTM == 1) {
                Al[k] = pack2(v[2 * k] - bf2f(f2bf(v[2 * k])),
                              v[2 * k + 1] - bf2f(f2bf(v[2 * k + 1])));
                Bl[k] = pack2(v[8 + 2 * k] - bf2f(f2bf(v[8 + 2 * k])),
                              v[9 + 2 * k] - bf2f(f2bf(v[9 + 2 * k])));
            }
        }
        uint32_t rh[4], rl[4];
        #pragma unroll
        for (int k = 0; k < 4; ++k)
            rh[k] = (uint32_t)__shfl_xor((int)(kh ? Ah[k] : Bh[k]), 32, 64);
        if constexpr (OUTM == 1) {
            #pragma unroll
            for (int k = 0; k < 4; ++k)
                rl[k] = (uint32_t)__shfl_xor((int)(kh ? Al[k] : Bl[k]), 32, 64);
        }
        const int cell = (coBase >> 4) + kh;
        size_t aoff = ((size_t)cell * H * W + (size_t)y * W + (x0 + n)) * 16;
        uint4 lo16, hi16;
        if (kh == 0) {
            lo16 = make_uint4(Ah[0], Ah[1], rh[0], rh[1]);
            hi16 = make_uint4(Ah[2], Ah[3], rh[2], rh[3]);
        } else {
            lo16 = make_uint4(rh[0], rh[1], Bh[0], Bh[1]);
            hi16 = make_uint4(rh[2], rh[3], Bh[2], Bh[3]);
        }
        *(uint4*)&outU[aoff] = lo16;
        *(uint4*)&outU[aoff + 8] = hi16;
        if constexpr (OUTM == 1) {
            uint4 lo16l, hi16l;
            if (kh == 0) {
                lo16l = make_uint4(Al[0], Al[1], rl[0], rl[1]);
                hi16l = make_uint4(Al[2], Al[3], rl[2], rl[3]);
            } else {
                lo16l = make_uint4(rl[0], rl[1], Bl[0], Bl[1]);
                hi16l = make_uint4(rl[2], rl[3], Bl[2], Bl[3]);
            }
            *(uint4*)&outU[aoff + LOUT] = lo16l;
            *(uint4*)&outU[aoff + LOUT + 8] = hi16l;
        }
    }
}

// ---------------- MFMA deconv (parity-split, W via LDS-DMA dbuf) ------------
template<int CIN, int COUT, int HIN, int WIN>
__global__ __launch_bounds__(256) void deconvM(const unsigned short* __restrict__ xA,
                                               const unsigned short* __restrict__ wsp,
                                               const float* __restrict__ bias,
                                               unsigned short* __restrict__ outA) {
    constexpr int HO = 2 * HIN, WO = 2 * WIN;
    constexpr int CH = CIN / 16;
    constexpr size_t LIN = (size_t)HIN * WIN * CIN;
    constexpr size_t LOUT = (size_t)HO * WO * COUT;
    constexpr int NXU = 5 * 33 * 4;
    constexpr int NLX = (NXU + 255) / 256;
    constexpr int NWU = 1152;
    __shared__ __align__(16) unsigned short sX[2][2][5][33][8];
    __shared__ __align__(16) unsigned short sW[2][2][2][9][32][8];
    const int tid = threadIdx.x;
    const int lane = tid & 63, wv = tid >> 6;
    const int n = lane & 31, kh = lane >> 5;
    const int x0 = blockIdx.x * 32;
    const int y0q = blockIdx.y * 4;
    const int cog = blockIdx.z;
    const uint4* wU4 = (const uint4*)wsp;

    f32x16 acc[4];
    #pragma unroll
    for (int d = 0; d < 4; ++d) acc[d] = (f32x16)0.0f;

    uint4 vx[NLX];
    auto LOADSX = [&](int ch) {
        #pragma unroll
        for (int i = 0; i < NLX; ++i) {
            int idx = tid + i * 256;
            int sub = idx & 3, hl = sub >> 1, khs = sub & 1;
            int cell = idx >> 2, row = cell / 33, col = cell - row * 33;
            int gy = y0q + row, gx = x0 + col;
            uint4 v = make_uint4(0u, 0u, 0u, 0u);
            if (idx < NXU && gy < HIN && gx < WIN)
                v = *(const uint4*)&xA[(size_t)hl * LIN +
                        ((size_t)(ch * HIN + gy) * WIN + gx) * 16 + khs * 8];
            vx[i] = v;
        }
    };
    auto WRITEX = [&]() {
        #pragma unroll
        for (int i = 0; i < NLX; ++i) {
            int idx = tid + i * 256;
            if (idx < NXU) {
                int sub = idx & 3, hl = sub >> 1, khs = sub & 1;
                int cell = idx >> 2, row = cell / 33, col = cell - row * 33;
                *(uint4*)&sX[hl][khs][row][col][0] = vx[i];
            }
        }
    };
    auto GLLW = [&](int buf, int ch) {
        const uint4* src = wU4 + (size_t)(cog * CH + ch) * NWU;
        uint4* dst = (uint4*)&sW[buf][0][0][0][0][0];
        #pragma unroll
        for (int i = 0; i < (NWU + 255) / 256; ++i) {
            int idx = tid + i * 256;
            if (idx < NWU) gll16(&src[idx], &dst[idx]);
        }
    };

    constexpr int SRC[9] = {3, 2, 2, 1, 0, 0, 1, 0, 0};
    constexpr int DST[9] = {3, 2, 3, 1, 0, 1, 3, 2, 3};

    LOADSX(0);
    GLLW(0, 0);
    for (int ch = 0; ch < CH; ++ch) {
        const int buf = ch & 1;
        __syncthreads();
        WRITEX();
        __syncthreads();
        if (ch + 1 < CH) { GLLW(buf ^ 1, ch + 1); LOADSX(ch + 1); }
        // pass 1: hi input fragments (wh*xh + wl*xh)
        {
            short8 xh[2][2];
            #pragma unroll
            for (int dy = 0; dy < 2; ++dy)
                #pragma unroll
                for (int dx = 0; dx < 2; ++dx)
                    xh[dy][dx] = *(const short8*)&sX[0][kh][wv + dy][n + dx][0];
            #pragma unroll
            for (int t = 0; t < 9; ++t) {
                short8 wh = *(const short8*)&sW[buf][0][kh][t][n][0];
                short8 wl = *(const short8*)&sW[buf][1][kh][t][n][0];
                const int dy = SRC[t] >> 1, dx = SRC[t] & 1, d = DST[t];
                acc[d] = __builtin_amdgcn_mfma_f32_32x32x16_bf16(wh, xh[dy][dx], acc[d], 0, 0, 0);
                acc[d] = __builtin_amdgcn_mfma_f32_32x32x16_bf16(wl, xh[dy][dx], acc[d], 0, 0, 0);
            }
        }
        // pass 2: lo input fragments (wh*xl)
        {
            short8 xl[2][2];
            #pragma unroll
            for (int dy = 0; dy < 2; ++dy)
                #pragma unroll
                for (int dx = 0; dx < 2; ++dx)
                    xl[dy][dx] = *(const short8*)&sX[1][kh][wv + dy][n + dx][0];
            #pragma unroll
            for (int t = 0; t < 9; ++t) {
                short8 wh = *(const short8*)&sW[buf][0][kh][t][n][0];
                const int dy = SRC[t] >> 1, dx = SRC[t] & 1, d = DST[t];
                acc[d] = __builtin_amdgcn_mfma_f32_32x32x16_bf16(wh, xl[dy][dx], acc[d], 0, 0, 0);
            }
        }
    }
    // ---- coalesced epilogue: per quad-row, lane writes 64B contiguous ----
    const int oyb = 2 * (y0q + wv);
    const int cell = cog * 2 + kh;
    #pragma unroll
    for (int py = 0; py < 2; ++py) {
        const int oy = oyb + py;
        uint4 cellw[2][2], celll[2][2];          // [px][half16]
        #pragma unroll
        for (int px = 0; px < 2; ++px) {
            const int pos = py * 2 + px;
            float v[16];
            #pragma unroll
            for (int reg = 0; reg < 16; ++reg) {
                int col = (reg & 3) + 8 * (reg >> 2) + 4 * kh;
                v[reg] = fmaxf(acc[pos][reg] + bias[cog * 32 + col], 0.f);
            }
            uint32_t Ah[4], Bh[4], Al[4], Bl[4];
            #pragma unroll
            for (int k = 0; k < 4; ++k) {
                Ah[k] = pack2(v[2 * k], v[2 * k + 1]);
                Bh[k] = pack2(v[8 + 2 * k], v[9 + 2 * k]);
                Al[k] = pack2(v[2 * k] - bf2f(f2bf(v[2 * k])),
                              v[2 * k + 1] - bf2f(f2bf(v[2 * k + 1])));
                Bl[k] = pack2(v[8 + 2 * k] - bf2f(f2bf(v[8 + 2 * k])),
                              v[9 + 2 * k] - bf2f(f2bf(v[9 + 2 * k])));
            }
            uint32_t rh[4], rl[4];
            #pragma unroll
            for (int k = 0; k < 4; ++k) {
                rh[k] = (uint32_t)__shfl_xor((int)(kh ? Ah[k] : Bh[k]), 32, 64);
                rl[k] = (uint32_t)__shfl_xor((int)(kh ? Al[k] : Bl[k]), 32, 64);
            }
            if (kh == 0) {
                cellw[px][0] = make_uint4(Ah[0], Ah[1], rh[0], rh[1]);
                cellw[px][1] = make_uint4(Ah[2], Ah[3], rh[2], rh[3]);
                celll[px][0] = make_uint4(Al[0], Al[1], rl[0], rl[1]);
                celll[px][1] = make_uint4(Al[2], Al[3], rl[2], rl[3]);
            } else {
                cellw[px][0] = make_uint4(rh[0], rh[1], Bh[0], Bh[1]);
                cellw[px][1] = make_uint4(rh[2], rh[3], Bh[2], Bh[3]);
                celll[px][0] = make_uint4(rl[0], rl[1], Bl[0], Bl[1]);
                celll[px][1] = make_uint4(rl[2], rl[3], Bl[2], Bl[3]);
            }
        }
        size_t aoff = ((size_t)cell * HO * WO + (size_t)oy * WO + 2 * (x0 + n)) * 16;
        *(uint4*)&outA[aoff]      = cellw[0][0];
        *(uint4*)&outA[aoff + 8]  = cellw[0][1];
        *(uint4*)&outA[aoff + 16] = cellw[1][0];
        *(uint4*)&outA[aoff + 24] = cellw[1][1];
        *(uint4*)&outA[aoff + LOUT]      = celll[0][0];
        *(uint4*)&outA[aoff + LOUT + 8]  = celll[0][1];
        *(uint4*)&outA[aoff + LOUT + 16] = celll[1][0];
        *(uint4*)&outA[aoff + LOUT + 24] = celll[1][1];
    }
}

// ---------------- final conv (128->3) + tanh, from bf16-hi A-format ----------
__global__ __launch_bounds__(256) void coA_kernel(const unsigned short* __restrict__ xA,
                                                  const float* __restrict__ wO,
                                                  const float* __restrict__ bo,
                                                  float* __restrict__ rec) {
    const int tid = threadIdx.x;
    const int lx = tid & 15, ly = tid >> 4;
    const int tx0 = (blockIdx.x & 15) * 16, ty0 = (blockIdx.x >> 4) * 16;
    const int ox = tx0 + lx, oy = ty0 + ly;
    float a0 = bo[0], a1 = bo[1], a2 = bo[2];
    for (int ch = 0; ch < 8; ++ch) {
        unsigned short cs[9][16];
        #pragma unroll
        for (int t = 0; t < 9; ++t) {
            const int gy = oy - 1 + t / 3, gx = ox - 1 + t % 3;
            uint4 v0 = make_uint4(0u, 0u, 0u, 0u), v1 = make_uint4(0u, 0u, 0u, 0u);
            if (gy >= 0 && gy < 256 && gx >= 0 && gx < 256) {
                const uint4* p = (const uint4*)&xA[((size_t)(ch * 256 + gy) * 256 + gx) * 16];
                v0 = p[0]; v1 = p[1];
            }
            *(uint4*)&cs[t][0] = v0;
            *(uint4*)&cs[t][8] = v1;
        }
        #pragma unroll
        for (int t = 0; t < 9; ++t) {
            const float* w0 = &wO[(0 * 9 + t) * 128 + ch * 16];
            const float* w1 = &wO[(1 * 9 + t) * 128 + ch * 16];
            const float* w2 = &wO[(2 * 9 + t) * 128 + ch * 16];
            #pragma unroll
            for (int j = 0; j < 16; ++j) {
                float v = bf2f(cs[t][j]);
                a0 = fmaf(v, w0[j], a0);
                a1 = fmaf(v, w1[j], a1);
                a2 = fmaf(v, w2[j], a2);
            }
        }
    }
    const int px = oy * 256 + ox;
    rec[px]                = tanhf(a0);
    rec[65536 + px]        = tanhf(a1);
    rec[2 * 65536 + px]    = tanhf(a2);
}

// ---------------------------------------------------------------------------
extern "C" void kernel_launch(void* const* d_in, const int* in_sizes, int n_in,
                              void* d_out, int out_size, void* d_ws, size_t ws_size,
                              hipStream_t stream) {
    const float* x   = (const float*)d_in[0];
    const float* We0 = (const float*)d_in[1];  const float* be0 = (const float*)d_in[2];
    const float* We1 = (const float*)d_in[3];  const float* be1 = (const float*)d_in[4];
    const float* Wi  = (const float*)d_in[5];  const float* bi  = (const float*)d_in[6];
    const float* Wd1 = (const float*)d_in[7];  const float* bd1 = (const float*)d_in[8];
    const float* Wc1 = (const float*)d_in[9];  const float* bc1 = (const float*)d_in[10];
    const float* Wd2 = (const float*)d_in[11]; const float* bd2 = (const float*)d_in[12];
    const float* Wc2 = (const float*)d_in[13]; const float* bc2 = (const float*)d_in[14];
    const float* Wd3 = (const float*)d_in[15]; const float* bd3 = (const float*)d_in[16];
    const float* Wc3 = (const float*)d_in[17]; const float* bc3 = (const float*)d_in[18];
    const float* Wo  = (const float*)d_in[19]; const float* bo  = (const float*)d_in[20];

    float* out    = (float*)d_out;
    float* rec    = out;               // [8,3,256,256]
    float* routed = out + 1572864;     // [8,4,32,32]
    float* grain  = out + 1605632;     // [8,16,16]
    float* ent    = out + 1607680;     // [8,16,16]

    // latent scratch in rec region (dead before first rec write)
    float* latf = out;                 // 32768 floats
    float* latc = out + 32768;         // 8192 floats
    float* thr  = out + 40960;         // 1 float
    unsigned short* slotC3 = (unsigned short*)(out + 1425408);

    // workspace: U activations [0,16.8M); slots [24M,32M); V = [32M,65.6M).
    char* ws8 = (char*)d_ws;
    unsigned short* Uu    = (unsigned short*)ws8;
    unsigned short* Vp    = (unsigned short*)(ws8 + (size_t)32 * 1024 * 1024);
    unsigned short* wspD1 = (unsigned short*)(ws8 + (size_t)24 * 1024 * 1024);
    unsigned short* wspC1 = (unsigned short*)(ws8 + (size_t)26 * 1024 * 1024 + 512 * 1024);
    unsigned short* wspD2 = (unsigned short*)(ws8 + (size_t)29 * 1024 * 1024);
    unsigned short* wspD3 = (unsigned short*)(ws8 + (size_t)30 * 1024 * 1024 + 256 * 1024);
    unsigned short* wspC2 = (unsigned short*)(ws8 + (size_t)31 * 1024 * 1024);
    float*          wspO  = (float*)(ws8 + (size_t)31 * 1024 * 1024 + 768 * 1024);

    // --- entropy / routing path ---
    enc_conv_kernel<<<128, 256, 0, stream>>>(x, We0, be0, latf, 8, 32);
    enc_conv_kernel<<<32, 256, 0, stream>>>(x, We1, be1, latc, 16, 16);
    entropy_kernel<<<2048, 256, 0, stream>>>(x, ent);
    median_kernel<<<1, 1024, 0, stream>>>(ent, thr);
    grain_kernel<<<8, 256, 0, stream>>>(ent, thr, grain);
    route_kernel<<<128, 256, 0, stream>>>(latf, latc, grain, routed);

    // --- weight pre-split: ONCE ---
    wsplit_all_kernel<<<7502, 256, 0, stream>>>(Wd1, Wc1, Wd2, Wc2, Wd3, Wc3, Wo,
                                                wspD1, wspC1, wspD2, wspC2, wspD3, slotC3,
                                                wspO);

    // --- decoder, per batch ---
    for (int b = 0; b < B; ++b) {
        const float* rb = routed + (size_t)b * 4 * 32 * 32;
        float* recb = rec + (size_t)b * 3 * 65536;
        conv3x3A<4, 256, 32, 32, 4, 16><<<dim3(16, 4, 1), 256, 0, stream>>>(rb, Wi, bi, Uu);
        deconvM<256, 256, 32, 32><<<dim3(1, 8, 8), 256, 0, stream>>>(Uu, wspD1, bd1, Vp);
        convM<256, 256, 64, 64, 1, 1><<<dim3(2, 16, 8), 256, 0, stream>>>(Vp, wspC1, bc1, Uu);
        deconvM<256, 128, 64, 64><<<dim3(2, 16, 4), 256, 0, stream>>>(Uu, wspD2, bd2, Vp);
        convM<128, 128, 128, 128, 1, 1><<<dim3(4, 32, 4), 256, 0, stream>>>(Vp, wspC2, bc2, Uu);
        deconvM<128, 128, 128, 128><<<dim3(4, 32, 4), 256, 0, stream>>>(Uu, wspD3, bd3, Vp);
        convM<128, 128, 256, 256, 2, 2><<<dim3(8, 32, 4), 256, 0, stream>>>(Vp, slotC3, bc3, Uu);
        coA_kernel<<<256, 256, 0, stream>>>(Uu, wspO, bo, recb);
    }
}